// Round 6
// baseline (426.726 us; speedup 1.0000x reference)
//
#include <hip/hip_runtime.h>
#include <hip/hip_bf16.h>

#define EPSF 1e-5f

typedef int v4i __attribute__((ext_vector_type(4)));
typedef int v16i __attribute__((ext_vector_type(16)));
typedef short v8s __attribute__((ext_vector_type(8)));

static constexpr int BB = 4, TT = 1024, DD = 2048, HH = 8192;
static constexpr int MROWS = BB * TT;                   // 4096
static constexpr long long WCOUNT = (long long)DD * HH; // 2^24 per weight

// ---------------------------------------------------------------- helpers

__device__ __forceinline__ void async_copy16(const void* g, void* l) {
  __builtin_amdgcn_global_load_lds(
      (const __attribute__((address_space(1))) unsigned int*)g,
      (__attribute__((address_space(3))) unsigned int*)l,
      16, 0, 0);
}

__device__ __forceinline__ int pack4(float a, float b, float c, float d,
                                     float scale, float lo, float hi) {
  int ia = (int)fminf(fmaxf(rintf(a * scale), lo), hi);
  int ib = (int)fminf(fmaxf(rintf(b * scale), lo), hi);
  int ic = (int)fminf(fmaxf(rintf(c * scale), lo), hi);
  int id = (int)fminf(fmaxf(rintf(d * scale), lo), hi);
  return (ia & 0xff) | ((ib & 0xff) << 8) | ((ic & 0xff) << 16) | ((id & 0xff) << 24);
}

__device__ __forceinline__ float abs4(float4 v) {
  return fmaxf(fmaxf(fabsf(v.x), fabsf(v.y)), fmaxf(fabsf(v.z), fabsf(v.w)));
}

// XCD-aware tile swizzle: id%8 class (heuristic XCD) owns a contiguous patch.
__device__ __forceinline__ void swizzle_tiles(int& mt, int& nt) {
  int Mt = gridDim.y, Nt = gridDim.x;
  int id = blockIdx.y * Nt + blockIdx.x;
  int c = id & 7, k = id >> 3;
  int pm = (Mt >= Nt) ? 4 : 2;
  int PM = Mt / pm, PN = Nt / (8 / pm);
  int pr = c % pm, pc = c / pm;
  mt = pr * PM + (k % PM);
  nt = pc * PN + (k / PM);
}

// ---------------------------------------------------------------- prep: |w| partial sums + act-quant x + rowMax zero (fused)
// blocks [0,4096): weight abs-sum partials (y = bid>>11, extent = bid&2047).
// blocks [4096,5120): x act-quant, wave = row (4 rows/block).
// blocks [5120,5136): zero the rowMax array (replaces hipMemsetAsync — keeps
// kernel_launch to plain kernel launches only, graph-capture-safe).

__global__ __launch_bounds__(256) void prep_kernel(
    const float* __restrict__ w1, const float* __restrict__ w2,
    const float* __restrict__ x, float* __restrict__ partials,
    signed char* __restrict__ xq, float* __restrict__ ascale,
    int* __restrict__ rowMax) {
  __shared__ float sm[4];
  const int bid = blockIdx.x, t = threadIdx.x;
  const int lane = t & 63, wv = t >> 6;

  if (bid < 4096) {
    const int y = bid >> 11, b = bid & 2047;
    const float4* w4 = (const float4*)(y ? w2 : w1);
    const long long base = (long long)b * 2048;
    float4 u[8];
    #pragma unroll
    for (int k = 0; k < 8; k++) u[k] = w4[base + t + k * 256];
    float s = 0.f;
    #pragma unroll
    for (int k = 0; k < 8; k++)
      s += fabsf(u[k].x) + fabsf(u[k].y) + fabsf(u[k].z) + fabsf(u[k].w);
    #pragma unroll
    for (int off = 32; off; off >>= 1) s += __shfl_down(s, off, 64);
    if (lane == 0) sm[wv] = s;
    __syncthreads();
    if (t == 0) partials[y * 2048 + b] = sm[0] + sm[1] + sm[2] + sm[3];
  } else if (bid < 5120) {
    int row = (bid - 4096) * 4 + wv;
    const float4* xr = (const float4*)(x + (size_t)row * DD);
    float4 v[8];
    #pragma unroll
    for (int j = 0; j < 8; j++) v[j] = xr[lane + j * 64];
    float m = 0.f;
    #pragma unroll
    for (int j = 0; j < 8; j++) m = fmaxf(m, abs4(v[j]));
    #pragma unroll
    for (int off = 32; off; off >>= 1) m = fmaxf(m, __shfl_down(m, off, 64));
    m = __shfl(m, 0, 64);
    float am = fmaxf(m, EPSF);
    float scale = 127.0f / am;
    int* out = (int*)(xq + (size_t)row * DD);
    #pragma unroll
    for (int j = 0; j < 8; j++)
      out[lane + j * 64] = pack4(v[j].x, v[j].y, v[j].z, v[j].w, scale, -128.f, 127.f);
    if (lane == 0) ascale[row] = am / 127.0f;
  } else {
    rowMax[(bid - 5120) * 256 + t] = 0;
  }
}

// ---------------------------------------------------------------- ternary quant

__global__ __launch_bounds__(256) void quant_w_kernel(
    const float* __restrict__ w1, const float* __restrict__ w2,
    const float* __restrict__ partials, float* __restrict__ meanw,
    signed char* __restrict__ q1, signed char* __restrict__ q2) {
  const int y = blockIdx.y, bid = blockIdx.x, t = threadIdx.x;
  const int lane = t & 63, wv = t >> 6;

  double d = 0.0;
  #pragma unroll
  for (int j = 0; j < 8; j++) d += (double)partials[y * 2048 + t + j * 256];
  #pragma unroll
  for (int off = 32; off; off >>= 1) d += __shfl_down(d, off, 64);
  __shared__ double smd[4];
  if (lane == 0) smd[wv] = d;
  __syncthreads();
  double sum = smd[0] + smd[1] + smd[2] + smd[3];
  float mean = fmaxf((float)(sum * (1.0 / (double)WCOUNT)), EPSF);
  if (bid == 0 && t == 0) meanw[y] = mean;
  float sc = 1.0f / mean;

  const float4* w4 = (const float4*)(y ? w2 : w1);
  int* q4 = (int*)(y ? q2 : q1);
  const long long base = (long long)bid * 2048;
  float4 u[8];
  #pragma unroll
  for (int k = 0; k < 8; k++) u[k] = w4[base + t + k * 256];
  #pragma unroll
  for (int k = 0; k < 8; k++)
    q4[base + t + k * 256] = pack4(u[k].x, u[k].y, u[k].z, u[k].w, sc, -1.f, 1.f);
}

// ---------------------------------------------------------------- act quant h (streaming; rowMax precomputed by GEMM1 epilogue)
// One block per row, no reduce: bmx comes from the GEMM1 atomicMax array.
// rowMax ALIASES a2's slot: each block reads rowMax[row] (all threads), then
// t0 overwrites it with a2[row] after a barrier.  Identical arithmetic to the
// old in-kernel reduce (same clamped int16 values feed the max).

__global__ __launch_bounds__(256) void quant_h_kernel(
    const short* __restrict__ h, signed char* __restrict__ hq,
    float* __restrict__ a2_rowmax, const float* __restrict__ a1,
    const float* __restrict__ meanw) {
  int row = blockIdx.x;
  int t = threadIdx.x;
  int bmx = ((const int*)a2_rowmax)[row];
  const v8s* hr = (const v8s*)(h + (size_t)row * HH);
  v8s v[4];
  #pragma unroll
  for (int i = 0; i < 4; i++) v[i] = hr[t + i * 256];
  float f = a1[row] * meanw[0];      // per-row dequant factor (exact ref path)
  float maxh = (float)bmx * f;       // == max_j fl(r_j*f): fl monotone, f>=0
  float am = fmaxf(maxh, EPSF);
  float scale = 127.0f / am;
  __syncthreads();                   // all rowMax reads done before t0's write
  if (t == 0) a2_rowmax[row] = am / 127.0f;
  int2* out = (int2*)(hq + (size_t)row * HH);
  #pragma unroll
  for (int i = 0; i < 4; i++) {
    int p0 = pack4((float)v[i][0] * f, (float)v[i][1] * f, (float)v[i][2] * f,
                   (float)v[i][3] * f, scale, -128.f, 127.f);
    int p1 = pack4((float)v[i][4] * f, (float)v[i][5] * f, (float)v[i][6] * f,
                   (float)v[i][7] * f, scale, -128.f, 127.f);
    out[t + i * 256] = int2{p0, p1};
  }
}

// ---------------------------------------------------------------- int8 GEMM: 256x128 tile, wave 128x64, BK=128, single-buffer
// Serial-sum model (validated R0/R2/R3/R4): per K-step {LDS-write | ds_read |
// MFMA} serialize; DS-read is the dominant term at wave 64x64 (1.0 read/MFMA).
// Wave tile 128x64 (MI=4,NJ=2 of 32x32x32) cuts it to 0.75: 6 ds_read_b128 ->
// 8 MFMA per ks.  BK=128 keeps CH=8: within each 16-lane phase of a
// ds_read_b128, the XOR swizzle c^(r&7) spreads 16 lanes over 8 chunk slots =
// 2-way = free (R4's CH=4 -> 4-way -> 2.5e7 conflicts confirmed the phase
// model).  acc = 8 x v16i = 128 VGPR; __launch_bounds__(256,2) -> 2 blocks/CU.
// MODE 1: relu -> int16 + per-row atomicMax into rowMax (feeds quant_h).
// MODE 0: scaled fp32 store.

template <int MODE>
__device__ __forceinline__ void gemm_body(
    const signed char* __restrict__ A, const signed char* __restrict__ B,
    void* __restrict__ Cout, const float* __restrict__ ascale,
    const float* __restrict__ wmean_p, int* __restrict__ rowMax,
    int M, int N, int K) {
  constexpr int BM = 256, BN = 128, BK = 128;
  constexpr int CH = BK / 16;          // 8 chunks of 16B per row
  constexpr int SEGR = 1024 / BK;      // 8 rows per 1KB segment
  constexpr int SPA = (BM * BK / 1024) / 4;  // 8 A-segments per wave
  constexpr int SPB = (BN * BK / 1024) / 4;  // 4 B-segments per wave
  __shared__ signed char As[BM * BK];  // 32 KB
  __shared__ signed char Bs[BN * BK];  // 16 KB

  const int t = threadIdx.x;
  const int lane = t & 63, wv = t >> 6;
  const int wm = wv >> 1, wn = wv & 1;
  int mt, nt;
  swizzle_tiles(mt, nt);
  const int m0 = mt * BM, n0 = nt * BN;
  const int hf = lane >> 5;            // K-half for 32x32 frags

  const signed char* aSrc[SPA];
  const signed char* bSrc[SPB];
  #pragma unroll
  for (int i = 0; i < SPA; i++) {
    int seg = wv * SPA + i;
    int r = seg * SEGR + lane / CH;
    int c = (lane % CH) ^ (r & (CH - 1));
    aSrc[i] = A + (size_t)(m0 + r) * K + c * 16;
  }
  #pragma unroll
  for (int i = 0; i < SPB; i++) {
    int seg = wv * SPB + i;
    int r = seg * SEGR + lane / CH;
    int c = (lane % CH) ^ (r & (CH - 1));
    bSrc[i] = B + (size_t)(n0 + r) * K + c * 16;
  }

  v16i acc[4][2];
  #pragma unroll
  for (int i = 0; i < 4; i++)
    #pragma unroll
    for (int j = 0; j < 2; j++) {
      v16i z = {0, 0, 0, 0, 0, 0, 0, 0, 0, 0, 0, 0, 0, 0, 0, 0};
      acc[i][j] = z;
    }

  int rowA[4], rowB[2];
  #pragma unroll
  for (int i = 0; i < 4; i++) rowA[i] = wm * 128 + i * 32 + (lane & 31);
  #pragma unroll
  for (int j = 0; j < 2; j++) rowB[j] = wn * 64 + j * 32 + (lane & 31);

  for (int k0 = 0; k0 < K; k0 += BK) {
    #pragma unroll
    for (int i = 0; i < SPA; i++)
      async_copy16(aSrc[i] + k0, &As[(wv * SPA + i) * 1024]);
    #pragma unroll
    for (int i = 0; i < SPB; i++)
      async_copy16(bSrc[i] + k0, &Bs[(wv * SPB + i) * 1024]);
    __syncthreads();
    #pragma unroll
    for (int ks = 0; ks < BK / 32; ks++) {
      v4i af[4], bf[2];
      #pragma unroll
      for (int j = 0; j < 2; j++) {
        int cb = (ks * 2 + hf) ^ (rowB[j] & (CH - 1));
        bf[j] = *(const v4i*)(Bs + rowB[j] * BK + cb * 16);
      }
      #pragma unroll
      for (int i = 0; i < 4; i++) {
        int ca = (ks * 2 + hf) ^ (rowA[i] & (CH - 1));
        af[i] = *(const v4i*)(As + rowA[i] * BK + ca * 16);
      }
      #pragma unroll
      for (int i = 0; i < 4; i++)
        #pragma unroll
        for (int j = 0; j < 2; j++)
          acc[i][j] = __builtin_amdgcn_mfma_i32_32x32x32_i8(af[i], bf[j], acc[i][j], 0, 0, 0);
    }
    __syncthreads();
  }

  if constexpr (MODE == 1) {
    short* C = (short*)Cout;
    #pragma unroll
    for (int i = 0; i < 4; i++) {
      #pragma unroll
      for (int e = 0; e < 16; e++) {
        int m = m0 + wm * 128 + i * 32 + (e & 3) + 8 * (e >> 2) + 4 * hf;
        int rm = 0;
        #pragma unroll
        for (int j = 0; j < 2; j++) {
          int n = n0 + wn * 64 + j * 32 + (lane & 31);
          int r = acc[i][j][e];
          r = r < 0 ? 0 : (r > 32767 ? 32767 : r);
          C[(size_t)m * N + n] = (short)r;
          rm = max(rm, r);
        }
        // row-max over the 32 columns held by this 32-lane half
        #pragma unroll
        for (int off = 16; off; off >>= 1) rm = max(rm, __shfl_xor(rm, off, 64));
        if ((lane & 31) == 0) atomicMax(&rowMax[m], rm);
      }
    }
  } else {
    float* C = (float*)Cout;
    float wmean = wmean_p[0];
    #pragma unroll
    for (int i = 0; i < 4; i++) {
      #pragma unroll
      for (int e = 0; e < 16; e++) {
        int m = m0 + wm * 128 + i * 32 + (e & 3) + 8 * (e >> 2) + 4 * hf;
        float f = ascale[m] * wmean;
        #pragma unroll
        for (int j = 0; j < 2; j++) {
          int n = n0 + wn * 64 + j * 32 + (lane & 31);
          C[(size_t)m * N + n] = (float)acc[i][j][e] * f;
        }
      }
    }
  }
}

__global__ __launch_bounds__(256, 2) void gemm_relu_i8(
    const signed char* __restrict__ A, const signed char* __restrict__ B,
    short* __restrict__ C, int* __restrict__ rowMax, int M, int N, int K) {
  gemm_body<1>(A, B, C, nullptr, nullptr, rowMax, M, N, K);
}

__global__ __launch_bounds__(256, 2) void gemm_out_i8(
    const signed char* __restrict__ A, const signed char* __restrict__ B,
    float* __restrict__ C, const float* __restrict__ ascale,
    const float* __restrict__ wmean_p, int M, int N, int K) {
  gemm_body<0>(A, B, C, ascale, wmean_p, nullptr, M, N, K);
}

// ---------------------------------------------------------------- launch

extern "C" void kernel_launch(void* const* d_in, const int* in_sizes, int n_in,
                              void* d_out, int out_size, void* d_ws, size_t ws_size,
                              hipStream_t stream) {
  const float* x  = (const float*)d_in[0];
  const float* w1 = (const float*)d_in[1];
  const float* w2 = (const float*)d_in[2];
  float* out = (float*)d_out;

  char* ws = (char*)d_ws;
  float* meanw = (float*)ws;                                // 2 f32
  float* partials = (float*)(ws + 1024);                    // 4096 f32 (16 KB)
  float* a1 = (float*)(ws + 20480);                         // 4096 f32
  float* a2 = (float*)(ws + 40960);                         // 4096 f32; aliased as int rowMax
  signed char* w1q = (signed char*)(ws + 65536);            // 16 MB
  signed char* w2q = w1q + (size_t)WCOUNT;                  // 16 MB
  signed char* xq  = w2q + (size_t)WCOUNT;                  // 8 MB
  signed char* hq  = xq + (size_t)MROWS * DD;               // 32 MB
  short* h16 = (short*)(hq + (size_t)MROWS * HH);           // 64 MB int16
  int* rowMax = (int*)a2;

  // prep: weight |.| partials (4096) + x act-quant (1024) + rowMax zero (16)
  prep_kernel<<<5136, 256, 0, stream>>>(w1, w2, x, partials, xq, a1, rowMax);
  quant_w_kernel<<<dim3(2048, 2), 256, 0, stream>>>(w1, w2, partials, meanw, w1q, w2q);
  // GEMM1: M=4096, N=8192, K=2048 — 256x128 tile, relu->int16 + rowMax
  gemm_relu_i8<<<dim3(HH / 128, MROWS / 256), 256, 0, stream>>>(
      xq, w1q, h16, rowMax, MROWS, HH, DD);
  quant_h_kernel<<<MROWS, 256, 0, stream>>>(h16, hq, a2, a1, meanw);
  // GEMM2: M=4096, N=2048, K=8192 — 256x128 tile, scaled fp32
  gemm_out_i8<<<dim3(DD / 128, MROWS / 256), 256, 0, stream>>>(
      hq, w2q, out, a2, &meanw[1], MROWS, DD, HH);
}

// Round 7
// 394.444 us; speedup vs baseline: 1.0818x; 1.0818x over previous
//
#include <hip/hip_runtime.h>
#include <hip/hip_bf16.h>

#define EPSF 1e-5f

typedef int v4i __attribute__((ext_vector_type(4)));
typedef int v16i __attribute__((ext_vector_type(16)));
typedef short v8s __attribute__((ext_vector_type(8)));

static constexpr int BB = 4, TT = 1024, DD = 2048, HH = 8192;
static constexpr int MROWS = BB * TT;                   // 4096
static constexpr long long WCOUNT = (long long)DD * HH; // 2^24 per weight

// ---------------------------------------------------------------- helpers

__device__ __forceinline__ void async_copy16(const void* g, void* l) {
  __builtin_amdgcn_global_load_lds(
      (const __attribute__((address_space(1))) unsigned int*)g,
      (__attribute__((address_space(3))) unsigned int*)l,
      16, 0, 0);
}

__device__ __forceinline__ int pack4(float a, float b, float c, float d,
                                     float scale, float lo, float hi) {
  int ia = (int)fminf(fmaxf(rintf(a * scale), lo), hi);
  int ib = (int)fminf(fmaxf(rintf(b * scale), lo), hi);
  int ic = (int)fminf(fmaxf(rintf(c * scale), lo), hi);
  int id = (int)fminf(fmaxf(rintf(d * scale), lo), hi);
  return (ia & 0xff) | ((ib & 0xff) << 8) | ((ic & 0xff) << 16) | ((id & 0xff) << 24);
}

__device__ __forceinline__ float abs4(float4 v) {
  return fmaxf(fmaxf(fabsf(v.x), fabsf(v.y)), fmaxf(fabsf(v.z), fabsf(v.w)));
}

// XCD-aware tile swizzle: id%8 class (heuristic XCD) owns a contiguous patch.
__device__ __forceinline__ void swizzle_tiles(int& mt, int& nt) {
  int Mt = gridDim.y, Nt = gridDim.x;
  int id = blockIdx.y * Nt + blockIdx.x;
  int c = id & 7, k = id >> 3;
  int pm = (Mt >= Nt) ? 4 : 2;
  int PM = Mt / pm, PN = Nt / (8 / pm);
  int pr = c % pm, pc = c / pm;
  mt = pr * PM + (k % PM);
  nt = pc * PN + (k / PM);
}

// ---------------------------------------------------------------- prep: |w| partial sums + act-quant x + rowMax zero (fused)
// blocks [0,4096): weight abs-sum partials (y = bid>>11, extent = bid&2047).
// blocks [4096,5120): x act-quant, wave = row (4 rows/block).
// blocks [5120,5136): zero the rowMax array (plain-kernel replacement for
// hipMemsetAsync; graph-capture-safe).

__global__ __launch_bounds__(256) void prep_kernel(
    const float* __restrict__ w1, const float* __restrict__ w2,
    const float* __restrict__ x, float* __restrict__ partials,
    signed char* __restrict__ xq, float* __restrict__ ascale,
    int* __restrict__ rowMax) {
  __shared__ float sm[4];
  const int bid = blockIdx.x, t = threadIdx.x;
  const int lane = t & 63, wv = t >> 6;

  if (bid < 4096) {
    const int y = bid >> 11, b = bid & 2047;
    const float4* w4 = (const float4*)(y ? w2 : w1);
    const long long base = (long long)b * 2048;
    float4 u[8];
    #pragma unroll
    for (int k = 0; k < 8; k++) u[k] = w4[base + t + k * 256];
    float s = 0.f;
    #pragma unroll
    for (int k = 0; k < 8; k++)
      s += fabsf(u[k].x) + fabsf(u[k].y) + fabsf(u[k].z) + fabsf(u[k].w);
    #pragma unroll
    for (int off = 32; off; off >>= 1) s += __shfl_down(s, off, 64);
    if (lane == 0) sm[wv] = s;
    __syncthreads();
    if (t == 0) partials[y * 2048 + b] = sm[0] + sm[1] + sm[2] + sm[3];
  } else if (bid < 5120) {
    int row = (bid - 4096) * 4 + wv;
    const float4* xr = (const float4*)(x + (size_t)row * DD);
    float4 v[8];
    #pragma unroll
    for (int j = 0; j < 8; j++) v[j] = xr[lane + j * 64];
    float m = 0.f;
    #pragma unroll
    for (int j = 0; j < 8; j++) m = fmaxf(m, abs4(v[j]));
    #pragma unroll
    for (int off = 32; off; off >>= 1) m = fmaxf(m, __shfl_down(m, off, 64));
    m = __shfl(m, 0, 64);
    float am = fmaxf(m, EPSF);
    float scale = 127.0f / am;
    int* out = (int*)(xq + (size_t)row * DD);
    #pragma unroll
    for (int j = 0; j < 8; j++)
      out[lane + j * 64] = pack4(v[j].x, v[j].y, v[j].z, v[j].w, scale, -128.f, 127.f);
    if (lane == 0) ascale[row] = am / 127.0f;
  } else {
    rowMax[(bid - 5120) * 256 + t] = 0;
  }
}

// ---------------------------------------------------------------- ternary quant

__global__ __launch_bounds__(256) void quant_w_kernel(
    const float* __restrict__ w1, const float* __restrict__ w2,
    const float* __restrict__ partials, float* __restrict__ meanw,
    signed char* __restrict__ q1, signed char* __restrict__ q2) {
  const int y = blockIdx.y, bid = blockIdx.x, t = threadIdx.x;
  const int lane = t & 63, wv = t >> 6;

  double d = 0.0;
  #pragma unroll
  for (int j = 0; j < 8; j++) d += (double)partials[y * 2048 + t + j * 256];
  #pragma unroll
  for (int off = 32; off; off >>= 1) d += __shfl_down(d, off, 64);
  __shared__ double smd[4];
  if (lane == 0) smd[wv] = d;
  __syncthreads();
  double sum = smd[0] + smd[1] + smd[2] + smd[3];
  float mean = fmaxf((float)(sum * (1.0 / (double)WCOUNT)), EPSF);
  if (bid == 0 && t == 0) meanw[y] = mean;
  float sc = 1.0f / mean;

  const float4* w4 = (const float4*)(y ? w2 : w1);
  int* q4 = (int*)(y ? q2 : q1);
  const long long base = (long long)bid * 2048;
  float4 u[8];
  #pragma unroll
  for (int k = 0; k < 8; k++) u[k] = w4[base + t + k * 256];
  #pragma unroll
  for (int k = 0; k < 8; k++)
    q4[base + t + k * 256] = pack4(u[k].x, u[k].y, u[k].z, u[k].w, sc, -1.f, 1.f);
}

// ---------------------------------------------------------------- act quant h (streaming; rowMax precomputed by GEMM1 epilogue)
// One block per row, no reduce: bmx comes from the GEMM1 atomicMax array.
// rowMax ALIASES a2's slot: each block reads rowMax[row] (all threads), then
// t0 overwrites it with a2[row] after a barrier.  Identical arithmetic to the
// old in-kernel reduce (same clamped int16 values feed the max).  Validated
// R6 (passed, absmax unchanged).

__global__ __launch_bounds__(256) void quant_h_kernel(
    const short* __restrict__ h, signed char* __restrict__ hq,
    float* __restrict__ a2_rowmax, const float* __restrict__ a1,
    const float* __restrict__ meanw) {
  int row = blockIdx.x;
  int t = threadIdx.x;
  int bmx = ((const int*)a2_rowmax)[row];
  const v8s* hr = (const v8s*)(h + (size_t)row * HH);
  v8s v[4];
  #pragma unroll
  for (int i = 0; i < 4; i++) v[i] = hr[t + i * 256];
  float f = a1[row] * meanw[0];      // per-row dequant factor (exact ref path)
  float maxh = (float)bmx * f;       // == max_j fl(r_j*f): fl monotone, f>=0
  float am = fmaxf(maxh, EPSF);
  float scale = 127.0f / am;
  __syncthreads();                   // all rowMax reads done before t0's write
  if (t == 0) a2_rowmax[row] = am / 127.0f;
  int2* out = (int2*)(hq + (size_t)row * HH);
  #pragma unroll
  for (int i = 0; i < 4; i++) {
    int p0 = pack4((float)v[i][0] * f, (float)v[i][1] * f, (float)v[i][2] * f,
                   (float)v[i][3] * f, scale, -128.f, 127.f);
    int p1 = pack4((float)v[i][4] * f, (float)v[i][5] * f, (float)v[i][6] * f,
                   (float)v[i][7] * f, scale, -128.f, 127.f);
    out[t + i * 256] = int2{p0, p1};
  }
}

// ---------------------------------------------------------------- int8 GEMM (R3 config, FROZEN — 91.7 us each, 0 conflicts)
// Five structural variants (2-barrier, ring-4 vmcnt, 8-phase, dbuf, wide
// wave-tile) all measured 91-131 us; this config is the best.  GEMM duration
// is NOT controlled by schedule or DS-read count at this occupancy (serial-sum
// model refuted R6) — do not re-open without new counter evidence.
// 128x128 tile, 4 waves 2x2, wave 64x64 via 2x2 mfma_i32_32x32x32_i8,
// global_load_lds w16, XOR 16B-chunk swizzle c^(r&(CH-1)) (2-way = free).
// C/D: col=lane&31, row=(reg&3)+8*(reg>>2)+4*(lane>>5) (m74/m101).
// MODE 1: relu -> int16 + per-row atomicMax into rowMax (feeds quant_h;
// validated R6).  MODE 0: scaled fp32 store.

template <int MODE, int BK>
__global__ __launch_bounds__(256) void gemm_i8_kernel(
    const signed char* __restrict__ A, const signed char* __restrict__ B,
    void* __restrict__ Cout, const float* __restrict__ ascale,
    const float* __restrict__ wmean_p, int* __restrict__ rowMax,
    int M, int N, int K) {
  constexpr int CH = BK / 16;
  constexpr int SEGROWS = 1024 / BK;
  constexpr int SPW = BK / 32;
  __shared__ signed char As[128 * BK];
  __shared__ signed char Bs[128 * BK];

  const int t = threadIdx.x;
  const int lane = t & 63, wv = t >> 6;
  const int wm = wv >> 1, wn = wv & 1;
  int mt, nt;
  swizzle_tiles(mt, nt);
  const int m0 = mt * 128, n0 = nt * 128;
  const int hf = lane >> 5;            // K-half for 32x32 frags

  const signed char* aSrc[SPW];
  const signed char* bSrc[SPW];
  #pragma unroll
  for (int i = 0; i < SPW; i++) {
    int seg = wv * SPW + i;
    int r = seg * SEGROWS + lane / CH;
    int c = (lane % CH) ^ (r & (CH - 1));
    aSrc[i] = A + (size_t)(m0 + r) * K + c * 16;
    bSrc[i] = B + (size_t)(n0 + r) * K + c * 16;
  }

  v16i acc[2][2];
  #pragma unroll
  for (int i = 0; i < 2; i++)
    #pragma unroll
    for (int j = 0; j < 2; j++) {
      v16i z = {0, 0, 0, 0, 0, 0, 0, 0, 0, 0, 0, 0, 0, 0, 0, 0};
      acc[i][j] = z;
    }

  int rowA[2], rowB[2];
  #pragma unroll
  for (int i = 0; i < 2; i++) {
    rowA[i] = wm * 64 + i * 32 + (lane & 31);
    rowB[i] = wn * 64 + i * 32 + (lane & 31);
  }

  for (int k0 = 0; k0 < K; k0 += BK) {
    #pragma unroll
    for (int i = 0; i < SPW; i++) {
      async_copy16(aSrc[i] + k0, &As[(wv * SPW + i) * 1024]);
      async_copy16(bSrc[i] + k0, &Bs[(wv * SPW + i) * 1024]);
    }
    __syncthreads();
    #pragma unroll
    for (int ks = 0; ks < BK / 32; ks++) {
      v4i af[2], bf[2];
      #pragma unroll
      for (int i = 0; i < 2; i++) {
        int ca = (ks * 2 + hf) ^ (rowA[i] & (CH - 1));
        af[i] = *(const v4i*)(As + rowA[i] * BK + ca * 16);
        int cb = (ks * 2 + hf) ^ (rowB[i] & (CH - 1));
        bf[i] = *(const v4i*)(Bs + rowB[i] * BK + cb * 16);
      }
      #pragma unroll
      for (int i = 0; i < 2; i++)
        #pragma unroll
        for (int j = 0; j < 2; j++)
          acc[i][j] = __builtin_amdgcn_mfma_i32_32x32x32_i8(af[i], bf[j], acc[i][j], 0, 0, 0);
    }
    __syncthreads();
  }

  if constexpr (MODE == 1) {
    short* C = (short*)Cout;
    #pragma unroll
    for (int i = 0; i < 2; i++) {
      #pragma unroll
      for (int e = 0; e < 16; e++) {
        int m = m0 + wm * 64 + i * 32 + (e & 3) + 8 * (e >> 2) + 4 * hf;
        int rm = 0;
        #pragma unroll
        for (int j = 0; j < 2; j++) {
          int n = n0 + wn * 64 + j * 32 + (lane & 31);
          int r = acc[i][j][e];
          r = r < 0 ? 0 : (r > 32767 ? 32767 : r);
          C[(size_t)m * N + n] = (short)r;
          rm = max(rm, r);
        }
        // row m's 32 columns live in this 32-lane half; reduce + one atomic
        #pragma unroll
        for (int off = 16; off; off >>= 1) rm = max(rm, __shfl_xor(rm, off, 64));
        if ((lane & 31) == 0) atomicMax(&rowMax[m], rm);
      }
    }
  } else {
    float* C = (float*)Cout;
    float wmean = wmean_p[0];
    #pragma unroll
    for (int i = 0; i < 2; i++) {
      #pragma unroll
      for (int e = 0; e < 16; e++) {
        int m = m0 + wm * 64 + i * 32 + (e & 3) + 8 * (e >> 2) + 4 * hf;
        float f = ascale[m] * wmean;
        #pragma unroll
        for (int j = 0; j < 2; j++) {
          int n = n0 + wn * 64 + j * 32 + (lane & 31);
          C[(size_t)m * N + n] = (float)acc[i][j][e] * f;
        }
      }
    }
  }
}

// ---------------------------------------------------------------- launch

extern "C" void kernel_launch(void* const* d_in, const int* in_sizes, int n_in,
                              void* d_out, int out_size, void* d_ws, size_t ws_size,
                              hipStream_t stream) {
  const float* x  = (const float*)d_in[0];
  const float* w1 = (const float*)d_in[1];
  const float* w2 = (const float*)d_in[2];
  float* out = (float*)d_out;

  char* ws = (char*)d_ws;
  float* meanw = (float*)ws;                                // 2 f32
  float* partials = (float*)(ws + 1024);                    // 4096 f32 (16 KB)
  float* a1 = (float*)(ws + 20480);                         // 4096 f32
  float* a2 = (float*)(ws + 40960);                         // 4096 f32; aliased as int rowMax
  signed char* w1q = (signed char*)(ws + 65536);            // 16 MB
  signed char* w2q = w1q + (size_t)WCOUNT;                  // 16 MB
  signed char* xq  = w2q + (size_t)WCOUNT;                  // 8 MB
  signed char* hq  = xq + (size_t)MROWS * DD;               // 32 MB
  short* h16 = (short*)(hq + (size_t)MROWS * HH);           // 64 MB int16
  int* rowMax = (int*)a2;

  // prep: weight |.| partials (4096) + x act-quant (1024) + rowMax zero (16)
  prep_kernel<<<5136, 256, 0, stream>>>(w1, w2, x, partials, xq, a1, rowMax);
  quant_w_kernel<<<dim3(2048, 2), 256, 0, stream>>>(w1, w2, partials, meanw, w1q, w2q);
  // GEMM1: M=4096, N=8192, K=2048 — BK=128, relu->int16 + rowMax
  gemm_i8_kernel<1, 128><<<dim3(HH / 128, MROWS / 128), 256, 0, stream>>>(
      xq, w1q, h16, nullptr, meanw, rowMax, MROWS, HH, DD);
  quant_h_kernel<<<MROWS, 256, 0, stream>>>(h16, hq, a2, a1, meanw);
  // GEMM2: M=4096, N=2048, K=8192 — BK=256, scaled fp32
  gemm_i8_kernel<0, 256><<<dim3(DD / 128, MROWS / 128), 256, 0, stream>>>(
      hq, w2q, out, a2, &meanw[1], nullptr, MROWS, DD, HH);
}

// Round 9
// 380.807 us; speedup vs baseline: 1.1206x; 1.0358x over previous
//
#include <hip/hip_runtime.h>
#include <hip/hip_bf16.h>

#define EPSF 1e-5f

typedef int v4i __attribute__((ext_vector_type(4)));
typedef int v16i __attribute__((ext_vector_type(16)));
typedef short v8s __attribute__((ext_vector_type(8)));

static constexpr int BB = 4, TT = 1024, DD = 2048, HH = 8192;
static constexpr int MROWS = BB * TT;                   // 4096
static constexpr long long WCOUNT = (long long)DD * HH; // 2^24 per weight

// ---------------------------------------------------------------- helpers

__device__ __forceinline__ void async_copy16(const void* g, void* l) {
  __builtin_amdgcn_global_load_lds(
      (const __attribute__((address_space(1))) unsigned int*)g,
      (__attribute__((address_space(3))) unsigned int*)l,
      16, 0, 0);
}

__device__ __forceinline__ int pack4(float a, float b, float c, float d,
                                     float scale, float lo, float hi) {
  int ia = (int)fminf(fmaxf(rintf(a * scale), lo), hi);
  int ib = (int)fminf(fmaxf(rintf(b * scale), lo), hi);
  int ic = (int)fminf(fmaxf(rintf(c * scale), lo), hi);
  int id = (int)fminf(fmaxf(rintf(d * scale), lo), hi);
  return (ia & 0xff) | ((ib & 0xff) << 8) | ((ic & 0xff) << 16) | ((id & 0xff) << 24);
}

__device__ __forceinline__ float abs4(float4 v) {
  return fmaxf(fmaxf(fabsf(v.x), fabsf(v.y)), fmaxf(fabsf(v.z), fabsf(v.w)));
}

// XCD-aware tile swizzle: id%8 class (heuristic XCD) owns a contiguous patch.
__device__ __forceinline__ void swizzle_tiles(int& mt, int& nt) {
  int Mt = gridDim.y, Nt = gridDim.x;
  int id = blockIdx.y * Nt + blockIdx.x;
  int c = id & 7, k = id >> 3;
  int pm = (Mt >= Nt) ? 4 : 2;
  int PM = Mt / pm, PN = Nt / (8 / pm);
  int pr = c % pm, pc = c / pm;
  mt = pr * PM + (k % PM);
  nt = pc * PN + (k / PM);
}

// ---------------------------------------------------------------- prep: |w| partial sums + act-quant x (fused)
// blocks [0,2048): weight abs-sum partials, 64 KB extent per block
//   (y = bid>>10, extent = bid&1023) -> 1024 partials per weight.
//   Bigger extents: grid 3072 fits in 1.5 co-resident batches (was 2.5).
// blocks [2048,3072): x act-quant, wave = row (4 rows/block).

__global__ __launch_bounds__(256) void prep_kernel(
    const float* __restrict__ w1, const float* __restrict__ w2,
    const float* __restrict__ x, float* __restrict__ partials,
    signed char* __restrict__ xq, float* __restrict__ ascale) {
  __shared__ float sm[4];
  const int bid = blockIdx.x, t = threadIdx.x;
  const int lane = t & 63, wv = t >> 6;

  if (bid < 2048) {
    const int y = bid >> 10, b = bid & 1023;
    const float4* w4 = (const float4*)(y ? w2 : w1);
    const long long base = (long long)b * 4096;
    float s = 0.f;
    #pragma unroll
    for (int k = 0; k < 16; k++) {
      float4 u = w4[base + t + k * 256];
      s += fabsf(u.x) + fabsf(u.y) + fabsf(u.z) + fabsf(u.w);
    }
    #pragma unroll
    for (int off = 32; off; off >>= 1) s += __shfl_down(s, off, 64);
    if (lane == 0) sm[wv] = s;
    __syncthreads();
    if (t == 0) partials[y * 1024 + b] = sm[0] + sm[1] + sm[2] + sm[3];
  } else {
    int row = (bid - 2048) * 4 + wv;
    const float4* xr = (const float4*)(x + (size_t)row * DD);
    float4 v[8];
    #pragma unroll
    for (int j = 0; j < 8; j++) v[j] = xr[lane + j * 64];
    float m = 0.f;
    #pragma unroll
    for (int j = 0; j < 8; j++) m = fmaxf(m, abs4(v[j]));
    #pragma unroll
    for (int off = 32; off; off >>= 1) m = fmaxf(m, __shfl_down(m, off, 64));
    m = __shfl(m, 0, 64);
    float am = fmaxf(m, EPSF);
    float scale = 127.0f / am;
    int* out = (int*)(xq + (size_t)row * DD);
    #pragma unroll
    for (int j = 0; j < 8; j++)
      out[lane + j * 64] = pack4(v[j].x, v[j].y, v[j].z, v[j].w, scale, -128.f, 127.f);
    if (lane == 0) ascale[row] = am / 127.0f;
  }
}

// ---------------------------------------------------------------- ternary quant
// Every block re-reduces the 1024 partials with an IDENTICAL tree
// (deterministic, L2-hit reads), then quantizes its 32 KB extent.

__global__ __launch_bounds__(256) void quant_w_kernel(
    const float* __restrict__ w1, const float* __restrict__ w2,
    const float* __restrict__ partials, float* __restrict__ meanw,
    signed char* __restrict__ q1, signed char* __restrict__ q2) {
  const int y = blockIdx.y, bid = blockIdx.x, t = threadIdx.x;
  const int lane = t & 63, wv = t >> 6;

  double d = 0.0;
  #pragma unroll
  for (int j = 0; j < 4; j++) d += (double)partials[y * 1024 + t + j * 256];
  #pragma unroll
  for (int off = 32; off; off >>= 1) d += __shfl_down(d, off, 64);
  __shared__ double smd[4];
  if (lane == 0) smd[wv] = d;
  __syncthreads();
  double sum = smd[0] + smd[1] + smd[2] + smd[3];
  float mean = fmaxf((float)(sum * (1.0 / (double)WCOUNT)), EPSF);
  if (bid == 0 && t == 0) meanw[y] = mean;
  float sc = 1.0f / mean;

  const float4* w4 = (const float4*)(y ? w2 : w1);
  int* q4 = (int*)(y ? q2 : q1);
  const long long base = (long long)bid * 2048;
  float4 u[8];
  #pragma unroll
  for (int k = 0; k < 8; k++) u[k] = w4[base + t + k * 256];
  #pragma unroll
  for (int k = 0; k < 8; k++)
    q4[base + t + k * 256] = pack4(u[k].x, u[k].y, u[k].z, u[k].w, sc, -1.f, 1.f);
}

// ---------------------------------------------------------------- act quant h (wave = row, barrier-free)
// R7's GEMM-epilogue rowMax fusion REVERTED: 160 shuffles/thread in the GEMM
// tail cost +24 us and 8.4e6 LDS conflicts (shuffles use the LDS permute
// path), vs <=8 us saved.  Row max is recomputed locally, at WAVE scope:
// 1 wave per row, 128 int16 per lane, 6 __shfl_down — no LDS, no
// __syncthreads.  Arithmetic identical to the verified R3 path.

__global__ __launch_bounds__(256) void quant_h_kernel(
    const short* __restrict__ h, signed char* __restrict__ hq,
    float* __restrict__ a2, const float* __restrict__ a1,
    const float* __restrict__ meanw) {
  int lane = threadIdx.x & 63, wv = threadIdx.x >> 6;
  int row = blockIdx.x * 4 + wv;
  const v8s* hr = (const v8s*)(h + (size_t)row * HH);
  v8s v[16];
  #pragma unroll
  for (int j = 0; j < 16; j++) v[j] = hr[lane + j * 64];
  int mx = 0;
  #pragma unroll
  for (int j = 0; j < 16; j++)
    #pragma unroll
    for (int e = 0; e < 8; e++) mx = max(mx, (int)v[j][e]);
  #pragma unroll
  for (int off = 32; off; off >>= 1) mx = max(mx, __shfl_down(mx, off, 64));
  mx = __shfl(mx, 0, 64);
  float f = a1[row] * meanw[0];      // per-row dequant factor (exact ref path)
  float maxh = (float)mx * f;        // == max_j fl(r_j*f): fl monotone, f>=0
  float am = fmaxf(maxh, EPSF);
  float scale = 127.0f / am;
  int2* out = (int2*)(hq + (size_t)row * HH);
  #pragma unroll
  for (int j = 0; j < 16; j++) {
    int p0 = pack4((float)v[j][0] * f, (float)v[j][1] * f, (float)v[j][2] * f,
                   (float)v[j][3] * f, scale, -128.f, 127.f);
    int p1 = pack4((float)v[j][4] * f, (float)v[j][5] * f, (float)v[j][6] * f,
                   (float)v[j][7] * f, scale, -128.f, 127.f);
    out[lane + j * 64] = int2{p0, p1};
  }
  if (lane == 0) a2[row] = am / 127.0f;
}

// ---------------------------------------------------------------- int8 GEMM (R3 config, FROZEN — ~92 us each, 0 conflicts)
// Five structural variants (2-barrier, ring-4 vmcnt, 8-phase, dbuf, wide
// wave-tile) measured 91-131 us; this config is the best.  GEMM duration is
// NOT controlled by schedule, DS-read count, or MFMA instr count at this
// occupancy (R2/R3/R6 nulls) — do not re-open without new counter evidence.
// Epilogue must stay shuffle-free (R7: cross-lane reduce in the tail = +24us).
// 128x128 tile, 4 waves 2x2, wave 64x64 via 2x2 mfma_i32_32x32x32_i8,
// global_load_lds w16, XOR 16B-chunk swizzle c^(r&(CH-1)) (2-way = free).
// C/D: col=lane&31, row=(reg&3)+8*(reg>>2)+4*(lane>>5) (m74/m101).
// MODE 1: relu -> int16 store.  MODE 0: scaled fp32 store.

template <int MODE, int BK>
__global__ __launch_bounds__(256) void gemm_i8_kernel(
    const signed char* __restrict__ A, const signed char* __restrict__ B,
    void* __restrict__ Cout, const float* __restrict__ ascale,
    const float* __restrict__ wmean_p, int M, int N, int K) {
  constexpr int CH = BK / 16;
  constexpr int SEGROWS = 1024 / BK;
  constexpr int SPW = BK / 32;
  __shared__ signed char As[128 * BK];
  __shared__ signed char Bs[128 * BK];

  const int t = threadIdx.x;
  const int lane = t & 63, wv = t >> 6;
  const int wm = wv >> 1, wn = wv & 1;
  int mt, nt;
  swizzle_tiles(mt, nt);
  const int m0 = mt * 128, n0 = nt * 128;
  const int hf = lane >> 5;            // K-half for 32x32 frags

  const signed char* aSrc[SPW];
  const signed char* bSrc[SPW];
  #pragma unroll
  for (int i = 0; i < SPW; i++) {
    int seg = wv * SPW + i;
    int r = seg * SEGROWS + lane / CH;
    int c = (lane % CH) ^ (r & (CH - 1));
    aSrc[i] = A + (size_t)(m0 + r) * K + c * 16;
    bSrc[i] = B + (size_t)(n0 + r) * K + c * 16;
  }

  v16i acc[2][2];
  #pragma unroll
  for (int i = 0; i < 2; i++)
    #pragma unroll
    for (int j = 0; j < 2; j++) {
      v16i z = {0, 0, 0, 0, 0, 0, 0, 0, 0, 0, 0, 0, 0, 0, 0, 0};
      acc[i][j] = z;
    }

  int rowA[2], rowB[2];
  #pragma unroll
  for (int i = 0; i < 2; i++) {
    rowA[i] = wm * 64 + i * 32 + (lane & 31);
    rowB[i] = wn * 64 + i * 32 + (lane & 31);
  }

  for (int k0 = 0; k0 < K; k0 += BK) {
    #pragma unroll
    for (int i = 0; i < SPW; i++) {
      async_copy16(aSrc[i] + k0, &As[(wv * SPW + i) * 1024]);
      async_copy16(bSrc[i] + k0, &Bs[(wv * SPW + i) * 1024]);
    }
    __syncthreads();
    #pragma unroll
    for (int ks = 0; ks < BK / 32; ks++) {
      v4i af[2], bf[2];
      #pragma unroll
      for (int i = 0; i < 2; i++) {
        int ca = (ks * 2 + hf) ^ (rowA[i] & (CH - 1));
        af[i] = *(const v4i*)(As + rowA[i] * BK + ca * 16);
        int cb = (ks * 2 + hf) ^ (rowB[i] & (CH - 1));
        bf[i] = *(const v4i*)(Bs + rowB[i] * BK + cb * 16);
      }
      #pragma unroll
      for (int i = 0; i < 2; i++)
        #pragma unroll
        for (int j = 0; j < 2; j++)
          acc[i][j] = __builtin_amdgcn_mfma_i32_32x32x32_i8(af[i], bf[j], acc[i][j], 0, 0, 0);
    }
    __syncthreads();
  }

  if constexpr (MODE == 1) {
    short* C = (short*)Cout;
    #pragma unroll
    for (int i = 0; i < 2; i++) {
      #pragma unroll
      for (int e = 0; e < 16; e++) {
        int m = m0 + wm * 64 + i * 32 + (e & 3) + 8 * (e >> 2) + 4 * hf;
        #pragma unroll
        for (int j = 0; j < 2; j++) {
          int n = n0 + wn * 64 + j * 32 + (lane & 31);
          int r = acc[i][j][e];
          r = r < 0 ? 0 : (r > 32767 ? 32767 : r);
          C[(size_t)m * N + n] = (short)r;
        }
      }
    }
  } else {
    float* C = (float*)Cout;
    float wmean = wmean_p[0];
    #pragma unroll
    for (int i = 0; i < 2; i++) {
      #pragma unroll
      for (int e = 0; e < 16; e++) {
        int m = m0 + wm * 64 + i * 32 + (e & 3) + 8 * (e >> 2) + 4 * hf;
        float f = ascale[m] * wmean;
        #pragma unroll
        for (int j = 0; j < 2; j++) {
          int n = n0 + wn * 64 + j * 32 + (lane & 31);
          C[(size_t)m * N + n] = (float)acc[i][j][e] * f;
        }
      }
    }
  }
}

// ---------------------------------------------------------------- launch

extern "C" void kernel_launch(void* const* d_in, const int* in_sizes, int n_in,
                              void* d_out, int out_size, void* d_ws, size_t ws_size,
                              hipStream_t stream) {
  const float* x  = (const float*)d_in[0];
  const float* w1 = (const float*)d_in[1];
  const float* w2 = (const float*)d_in[2];
  float* out = (float*)d_out;

  char* ws = (char*)d_ws;
  float* meanw = (float*)ws;                                // 2 f32
  float* partials = (float*)(ws + 1024);                    // 2048 f32 (8 KB)
  float* a1 = (float*)(ws + 20480);                         // 4096 f32
  float* a2 = (float*)(ws + 40960);                         // 4096 f32
  signed char* w1q = (signed char*)(ws + 65536);            // 16 MB
  signed char* w2q = w1q + (size_t)WCOUNT;                  // 16 MB
  signed char* xq  = w2q + (size_t)WCOUNT;                  // 8 MB
  signed char* hq  = xq + (size_t)MROWS * DD;               // 32 MB
  short* h16 = (short*)(hq + (size_t)MROWS * HH);           // 64 MB int16

  // prep: weight |.| partials (2048 x 64KB) + x act-quant (1024)
  prep_kernel<<<3072, 256, 0, stream>>>(w1, w2, x, partials, xq, a1);
  quant_w_kernel<<<dim3(2048, 2), 256, 0, stream>>>(w1, w2, partials, meanw, w1q, w2q);
  // GEMM1: M=4096, N=8192, K=2048 — BK=128, relu->int16
  gemm_i8_kernel<1, 128><<<dim3(HH / 128, MROWS / 128), 256, 0, stream>>>(
      xq, w1q, h16, nullptr, meanw, MROWS, HH, DD);
  quant_h_kernel<<<MROWS / 4, 256, 0, stream>>>(h16, hq, a2, a1, meanw);
  // GEMM2: M=4096, N=2048, K=8192 — BK=256, scaled fp32
  gemm_i8_kernel<0, 256><<<dim3(DD / 128, MROWS / 128), 256, 0, stream>>>(
      hq, w2q, out, a2, &meanw[1], MROWS, DD, HH);
}